// Round 4
// baseline (273.050 us; speedup 1.0000x reference)
//
#include <hip/hip_runtime.h>
#include <cstdint>
#include <cstddef>
#include <cmath>

typedef __bf16 bf16_t;
typedef bf16_t bf16x8 __attribute__((ext_vector_type(8)));
typedef bf16_t bf16x4 __attribute__((ext_vector_type(4)));
typedef float f32x4 __attribute__((ext_vector_type(4)));

constexpr int kB = 4;
constexpr int kS = 2048;
constexpr int kD = 1024;

typedef __attribute__((address_space(1))) void as1void;
typedef __attribute__((address_space(3))) void as3void;

__device__ __forceinline__ void gload16(const void* g, void* l) {
  __builtin_amdgcn_global_load_lds((as1void*)g, (as3void*)l, 16, 0, 0);
}

// ===========================================================================
// 2-phase double-buffered GEMM mainloop, BK=32, chunked conflict-free LDS.
// acc[4][4] += A[TM][K] * B[TN][K]^T (row-major bf16); wave tile 64x64.
// Chunked slot layout: elem = rg*512 + kg*128 + fr*8 (row=rg*16+fr, col=kg*8)
//   -> every 16-row frag ds_read_b128 is 64-lane-contiguous 1024B: 0 conflicts.
//   Staged via linear gload_lds with permuted GLOBAL source (both-sides rule).
// Occupancy does the overlap: 2-4 blocks/CU cover the per-tile barrier drain.
// ===========================================================================
template <int TM, int TN, int NTHR>
__device__ __forceinline__ void gemm2ph(
    const bf16_t* __restrict__ A, int lda,
    const bf16_t* __restrict__ B, int ldb,
    int nk, bf16_t* lds, f32x4 acc[4][4]) {
  constexpr int WND = TN / 64;            // waves along N
  constexpr int IA = TM * 4 / NTHR;       // A 16B-slots per thread
  constexpr int IB = TN * 4 / NTHR;
  constexpr int BUF = (TM + TN) * 32;     // elems per buffer
  const int tid = threadIdx.x;
  const int wid = tid >> 6, lane = tid & 63;
  const int wm = wid / WND, wn = wid % WND;
  const int fr = lane & 15, kg = lane >> 4;

  const bf16_t* gA[IA]; int oA[IA];
#pragma unroll
  for (int i = 0; i < IA; ++i) {          // u = [rg][kg][fr] -> row,col
    const int u = tid + i * NTHR;
    const int r = ((u >> 6) << 4) | (u & 15);
    const int c = ((u >> 4) & 3) << 3;
    gA[i] = A + (size_t)r * lda + c;
    oA[i] = u * 8;
  }
  const bf16_t* gB[IB]; int oB[IB];
#pragma unroll
  for (int i = 0; i < IB; ++i) {
    const int u = tid + i * NTHR;
    const int r = ((u >> 6) << 4) | (u & 15);
    const int c = ((u >> 4) & 3) << 3;
    gB[i] = B + (size_t)r * ldb + c;
    oB[i] = TM * 32 + u * 8;
  }
  // prologue: stage tile 0 into buffer 0
#pragma unroll
  for (int i = 0; i < IA; ++i) gload16(gA[i], lds + oA[i]);
#pragma unroll
  for (int i = 0; i < IB; ++i) gload16(gB[i], lds + oB[i]);
  __syncthreads();

  int cur = 0;
  const int aoff = kg * 128 + fr * 8;
  for (int t = 0; t < nk; ++t) {
    if (t + 1 < nk) {                     // prefetch next tile into other buffer
      bf16_t* nb = lds + (cur ^ 1) * BUF;
#pragma unroll
      for (int i = 0; i < IA; ++i) gload16(gA[i] + (t + 1) * 32, nb + oA[i]);
#pragma unroll
      for (int i = 0; i < IB; ++i) gload16(gB[i] + (t + 1) * 32, nb + oB[i]);
    }
    const bf16_t* cb = lds + cur * BUF;
    bf16x8 aF[4], bF[4];
#pragma unroll
    for (int m = 0; m < 4; ++m)
      aF[m] = *(const bf16x8*)(cb + (wm * 4 + m) * 512 + aoff);
#pragma unroll
    for (int n = 0; n < 4; ++n)
      bF[n] = *(const bf16x8*)(cb + TM * 32 + (wn * 4 + n) * 512 + aoff);
#pragma unroll
    for (int m = 0; m < 4; ++m)
#pragma unroll
      for (int n = 0; n < 4; ++n)
        acc[m][n] = __builtin_amdgcn_mfma_f32_16x16x32_bf16(aF[m], bF[n],
                                                            acc[m][n], 0, 0, 0);
    __syncthreads();                      // drains lgkm + vmcnt (next tile in)
    cur ^= 1;
  }
}

// C/D frag (16x16x32, verified m89/m91): col = lane&15, row = (lane>>4)*4 + i.
// out row = m0 + wm*64 + m*16 + (lane>>4)*4 + i; col = n0 + wn*64 + n*16 + (lane&15)

// ------------- fused QKV: 256x128 tile, 512 thr, 2 blk/CU, grid 768 ---------
__global__ __launch_bounds__(512, 4)
void k_qkv(const bf16_t* __restrict__ A, const bf16_t* __restrict__ WT,
           const float* __restrict__ bq, const float* __restrict__ bk,
           const float* __restrict__ bv, bf16_t* __restrict__ Out) {
  __shared__ bf16_t lds[2 * (256 + 128) * 32];   // 48KB
  const int id = blockIdx.x;                     // 768 = 32 mb x 24 nbb
  const int swz = (id & 7) * 96 + (id >> 3);     // XCD-chunked (768%8==0)
  const int mb = swz / 24, nbb = swz % 24;
  const int which = nbb >> 3;                    // 0=Q,1=K,2=V
  const int m0 = mb * 256, n0 = (nbb & 7) * 128;
  f32x4 acc[4][4] = {};
  gemm2ph<256, 128, 512>(A + (size_t)m0 * kD, kD,
                         WT + (size_t)which * kD * kD + (size_t)n0 * kD, kD,
                         kD / 32, lds, acc);
  const float* bias = which == 0 ? bq : which == 1 ? bk : bv;
  const int lane = threadIdx.x & 63, wid = threadIdx.x >> 6;
  const int wm = wid >> 1, wn = wid & 1, fr = lane & 15, kgr = lane >> 4;
  if (which < 2) {
    bf16_t* C = Out + (size_t)which * kB * kS * kD;
#pragma unroll
    for (int n = 0; n < 4; ++n) {
      const int col = n0 + wn * 64 + n * 16 + fr;
      const float bvv = bias[col];
#pragma unroll
      for (int m = 0; m < 4; ++m)
#pragma unroll
        for (int i = 0; i < 4; ++i) {
          const int row = m0 + wm * 64 + m * 16 + kgr * 4 + i;
          C[(size_t)row * kD + col] = (bf16_t)(acc[m][n][i] + bvv);
        }
    }
  } else {  // V -> VT[b][d][s]
    bf16_t* VT = Out + (size_t)2 * kB * kS * kD;
#pragma unroll
    for (int n = 0; n < 4; ++n) {
      const int col = n0 + wn * 64 + n * 16 + fr;
      const float bvv = bias[col];
#pragma unroll
      for (int m = 0; m < 4; ++m)
#pragma unroll
        for (int i = 0; i < 4; ++i) {
          const int row = m0 + wm * 64 + m * 16 + kgr * 4 + i;
          const int b = row >> 11, s = row & (kS - 1);
          VT[((size_t)b * kD + col) * kS + s] = (bf16_t)(acc[m][n][i] + bvv);
        }
    }
  }
}

// ------------- scores = Q*K^T/32: 128x128, triangular grid ------------------
__global__ __launch_bounds__(256, 4)
void k_scores(const bf16_t* __restrict__ Q, const bf16_t* __restrict__ K,
              float* __restrict__ Sc) {
  const int t = blockIdx.x, b = blockIdx.y;      // t in [0,136)
  int by = (int)((sqrtf(8.f * t + 1.f) - 1.f) * 0.5f);
  while ((by + 1) * (by + 2) / 2 <= t) ++by;
  while (by * (by + 1) / 2 > t) --by;
  const int bx = t - by * (by + 1) / 2;
  __shared__ bf16_t lds[2 * 256 * 32];           // 32KB
  const int m0 = by * 128, n0 = bx * 128;
  f32x4 acc[4][4] = {};
  gemm2ph<128, 128, 256>(Q + (size_t)b * kS * kD + (size_t)m0 * kD, kD,
                         K + (size_t)b * kS * kD + (size_t)n0 * kD, kD,
                         kD / 32, lds, acc);
  float* Sb = Sc + (size_t)b * kS * kS;
  const int lane = threadIdx.x & 63, wid = threadIdx.x >> 6;
  const int wm = wid >> 1, wn = wid & 1, fr = lane & 15, kgr = lane >> 4;
#pragma unroll
  for (int n = 0; n < 4; ++n) {
    const int col = n0 + wn * 64 + n * 16 + fr;
#pragma unroll
    for (int m = 0; m < 4; ++m)
#pragma unroll
      for (int i = 0; i < 4; ++i) {
        const int row = m0 + wm * 64 + m * 16 + kgr * 4 + i;
        Sb[(size_t)row * kS + col] = acc[m][n][i] * 0.03125f;
      }
  }
}

// ------------- attn_out = P*V: 128x128, causal K-limit, LPT -----------------
__global__ __launch_bounds__(256, 4)
void k_pv(const bf16_t* __restrict__ P, const bf16_t* __restrict__ VT,
          bf16_t* __restrict__ AO) {
  const int bx = blockIdx.x, b = blockIdx.z;
  const int by = (int)gridDim.y - 1 - (int)blockIdx.y;  // heavy-first
  __shared__ bf16_t lds[2 * 256 * 32];
  const int m0 = by * 128, n0 = bx * 128;
  const int nk = (m0 + 128) / 32;                // P zeros beyond q_max
  f32x4 acc[4][4] = {};
  gemm2ph<128, 128, 256>(P + (size_t)b * kS * kS + (size_t)m0 * kS, kS,
                         VT + (size_t)b * kD * kS + (size_t)n0 * kS, kS,
                         nk, lds, acc);
  bf16_t* AOb = AO + (size_t)b * kS * kD;
  const int lane = threadIdx.x & 63, wid = threadIdx.x >> 6;
  const int wm = wid >> 1, wn = wid & 1, fr = lane & 15, kgr = lane >> 4;
#pragma unroll
  for (int n = 0; n < 4; ++n) {
    const int col = n0 + wn * 64 + n * 16 + fr;
#pragma unroll
    for (int m = 0; m < 4; ++m)
#pragma unroll
      for (int i = 0; i < 4; ++i) {
        const int row = m0 + wm * 64 + m * 16 + kgr * 4 + i;
        AOb[(size_t)row * kD + col] = (bf16_t)acc[m][n][i];
      }
  }
}

// ------------- out = AO*Wo^T + bo (fp32): 128x128, grid 512 swizzled --------
__global__ __launch_bounds__(256, 4)
void k_out(const bf16_t* __restrict__ A, const bf16_t* __restrict__ Bw,
           const float* __restrict__ bias, float* __restrict__ C) {
  __shared__ bf16_t lds[2 * 256 * 32];
  const int id = blockIdx.x;                     // 512 = 64 mb x 8 nb
  const int swz = (id & 7) * 64 + (id >> 3);
  const int m0 = (swz >> 3) * 128, n0 = (swz & 7) * 128;
  f32x4 acc[4][4] = {};
  gemm2ph<128, 128, 256>(A + (size_t)m0 * kD, kD, Bw + (size_t)n0 * kD, kD,
                         kD / 32, lds, acc);
  const int lane = threadIdx.x & 63, wid = threadIdx.x >> 6;
  const int wm = wid >> 1, wn = wid & 1, fr = lane & 15, kgr = lane >> 4;
#pragma unroll
  for (int n = 0; n < 4; ++n) {
    const int col = n0 + wn * 64 + n * 16 + fr;
    const float bvv = bias[col];
#pragma unroll
    for (int m = 0; m < 4; ++m)
#pragma unroll
      for (int i = 0; i < 4; ++i) {
        const int row = m0 + wm * 64 + m * 16 + kgr * 4 + i;
        C[(size_t)row * kD + col] = acc[m][n][i] + bvv;
      }
  }
}

// ------------- row softmax (causal), fp32 -> d_out, bf16 -> ws --------------
__global__ __launch_bounds__(256)
void k_softmax(float* __restrict__ P, bf16_t* __restrict__ Pb) {
  const int row = blockIdx.x;          // 0..8191
  const int q = row & (kS - 1);
  float* p = P + (size_t)row * kS;
  bf16_t* pb = Pb + (size_t)row * kS;
  const int L = q + 1;
  __shared__ float buf[kS];
  __shared__ float red[8];
  const int tid = threadIdx.x;
  float4* b4 = (float4*)buf;
  const float4* p4 = (const float4*)p;
  if (tid * 4 < L) b4[tid] = p4[tid];
  if (1024 + tid * 4 < L) b4[tid + 256] = p4[tid + 256];
  __syncthreads();
  float mx = -1e30f;
  for (int k = tid; k < L; k += 256) mx = fmaxf(mx, buf[k]);
#pragma unroll
  for (int s2 = 32; s2 >= 1; s2 >>= 1) mx = fmaxf(mx, __shfl_xor(mx, s2));
  if ((tid & 63) == 0) red[tid >> 6] = mx;
  __syncthreads();
  mx = fmaxf(fmaxf(red[0], red[1]), fmaxf(red[2], red[3]));
  float sm = 0.f;
  for (int k = tid; k < L; k += 256) {
    const float e = __expf(buf[k] - mx);
    buf[k] = e;
    sm += e;
  }
#pragma unroll
  for (int s2 = 32; s2 >= 1; s2 >>= 1) sm += __shfl_xor(sm, s2);
  if ((tid & 63) == 0) red[4 + (tid >> 6)] = sm;
  __syncthreads();
  const float inv = 1.f / (red[4] + red[5] + red[6] + red[7]);
  for (int k = tid; k < L; k += 256) {
    const float v = buf[k] * inv;
    p[k] = v;
    pb[k] = (bf16_t)v;
  }
  for (int k = L + tid; k < kS; k += 256) {
    p[k] = 0.f;
    pb[k] = (bf16_t)0.f;
  }
}

// ------------- fused prep: z<4 weight transpose->bf16, z==4 x->bf16 ----------
__global__ __launch_bounds__(256)
void k_prep(const float* __restrict__ X, bf16_t* __restrict__ Y,
            const float* __restrict__ W0, const float* __restrict__ W1,
            const float* __restrict__ W2, const float* __restrict__ W3,
            bf16_t* __restrict__ T0, bf16_t* __restrict__ T1,
            bf16_t* __restrict__ T2, bf16_t* __restrict__ T3) {
  const int tx = threadIdx.x & 31, ty = threadIdx.x >> 5;
  if (blockIdx.z == 4) {                 // x fp32 -> bf16, grid-stride
    const size_t n4 = (size_t)kB * kS * kD / 4;
    size_t i = ((size_t)blockIdx.y * 32 + blockIdx.x) * 256 + threadIdx.x;
    const size_t stride = (size_t)1024 * 256;
    const float4* X4 = (const float4*)X;
    bf16x4* Y4 = (bf16x4*)Y;
    for (; i < n4; i += stride) {
      const float4 v = X4[i];
      bf16x4 o = {(bf16_t)v.x, (bf16_t)v.y, (bf16_t)v.z, (bf16_t)v.w};
      Y4[i] = o;
    }
    return;
  }
  const float* W = blockIdx.z == 0 ? W0 : blockIdx.z == 1 ? W1 : blockIdx.z == 2 ? W2 : W3;
  bf16_t* T = blockIdx.z == 0 ? T0 : blockIdx.z == 1 ? T1 : blockIdx.z == 2 ? T2 : T3;
  __shared__ float t[32][33];
  const int x0 = blockIdx.x * 32, y0 = blockIdx.y * 32;
#pragma unroll
  for (int j = 0; j < 4; ++j)
    t[ty + 8 * j][tx] = W[(size_t)(y0 + ty + 8 * j) * kD + x0 + tx];
  __syncthreads();
#pragma unroll
  for (int j = 0; j < 4; ++j)
    T[(size_t)(x0 + ty + 8 * j) * kD + y0 + tx] = (bf16_t)t[tx][ty + 8 * j];
}

extern "C" void kernel_launch(void* const* d_in, const int* in_sizes, int n_in,
                              void* d_out, int out_size, void* d_ws, size_t ws_size,
                              hipStream_t stream) {
  (void)in_sizes; (void)n_in; (void)out_size; (void)ws_size;
  const float* x  = (const float*)d_in[0];
  // d_in[1] = mask: tril(ones) by construction -> causality hardcoded
  const float* Wq = (const float*)d_in[2];
  const float* bq = (const float*)d_in[3];
  const float* Wk = (const float*)d_in[4];
  const float* bk = (const float*)d_in[5];
  const float* Wv = (const float*)d_in[6];
  const float* bv = (const float*)d_in[7];
  const float* Wo = (const float*)d_in[8];
  const float* bo = (const float*)d_in[9];

  float* out  = (float*)d_out;                       // [4,2048,1024] fp32
  float* Pout = out + (size_t)kB * kS * kD;          // [4,2048,2048] fp32

  bf16_t* WqT = (bf16_t*)d_ws;                       // [3][1024][1024] packed + WoT
  bf16_t* WkT = WqT + (size_t)kD * kD;
  bf16_t* WvT = WkT + (size_t)kD * kD;
  bf16_t* WoT = WvT + (size_t)kD * kD;
  bf16_t* Qb  = WoT + (size_t)kD * kD;               // Q,K row-major; VT transposed
  bf16_t* Kb  = Qb + (size_t)kB * kS * kD;
  bf16_t* VTb = Kb + (size_t)kB * kS * kD;
  bf16_t* Pb  = VTb + (size_t)kB * kS * kD;
  bf16_t* AOb = Pb + (size_t)kB * kS * kS;
  bf16_t* xb  = AOb + (size_t)kB * kS * kD;

  k_prep<<<dim3(32, 32, 5), 256, 0, stream>>>(x, xb, Wq, Wk, Wv, Wo,
                                              WqT, WkT, WvT, WoT);
  k_qkv<<<768, 512, 0, stream>>>(xb, WqT, bq, bk, bv, Qb);
  k_scores<<<dim3(136, kB), 256, 0, stream>>>(Qb, Kb, Pout);
  k_softmax<<<kB * kS, 256, 0, stream>>>(Pout, Pb);
  k_pv<<<dim3(8, 16, kB), 256, 0, stream>>>(Pb, VTb, AOb);
  k_out<<<512, 256, 0, stream>>>(AOb, WoT, bo, out);
}

// Round 5
// 234.217 us; speedup vs baseline: 1.1658x; 1.1658x over previous
//
#include <hip/hip_runtime.h>
#include <cstdint>
#include <cstddef>
#include <cmath>

typedef __bf16 bf16_t;
typedef bf16_t bf16x8 __attribute__((ext_vector_type(8)));
typedef bf16_t bf16x4 __attribute__((ext_vector_type(4)));
typedef float f32x4 __attribute__((ext_vector_type(4)));

constexpr int kB = 4;
constexpr int kS = 2048;
constexpr int kD = 1024;
constexpr int BM = 128, BN = 128, BK = 32;
constexpr int TILE_ELEMS = (BM + BN) * BK;   // 8192 bf16 = 16KB per buffer

typedef __attribute__((address_space(1))) void as1void;
typedef __attribute__((address_space(3))) void as3void;

__device__ __forceinline__ void gload16(const void* g, void* l) {
  __builtin_amdgcn_global_load_lds((as1void*)g, (as3void*)l, 16, 0, 0);
}

__device__ __forceinline__ void wgbar() {
  asm volatile("" ::: "memory");
  __builtin_amdgcn_s_barrier();
  asm volatile("" ::: "memory");
}

// ===========================================================================
// R2-proven 2-phase mainloop (128x128, 4 waves, linear LDS). Untouched.
// ===========================================================================
__device__ __forceinline__ void gemm_mainloop(
    const bf16_t* __restrict__ A, int lda,
    const bf16_t* __restrict__ B, int ldb,
    int ksteps, bf16_t* lds, f32x4 acc[4][4]) {
  const int tid = threadIdx.x;
  const int w = tid >> 6, lane = tid & 63;
  const int srow = lane >> 2;
  const int scol = (lane & 3) << 3;
  const int wr = (w >> 1) << 6, wc = (w & 1) << 6;
  const int fr = lane & 15, kg = lane >> 4;

  const bf16_t* ga0 = A + (size_t)(w * 16 + srow) * lda + scol;
  const bf16_t* ga1 = A + (size_t)(64 + w * 16 + srow) * lda + scol;
  const bf16_t* gb0 = B + (size_t)(w * 16 + srow) * ldb + scol;
  const bf16_t* gb1 = B + (size_t)(64 + w * 16 + srow) * ldb + scol;
  const int oa0 = (w * 16) * BK;
  const int oa1 = (64 + w * 16) * BK;
  const int ob0 = BM * BK + (w * 16) * BK;
  const int ob1 = BM * BK + (64 + w * 16) * BK;

  gload16(ga0, lds + oa0);
  gload16(ga1, lds + oa1);
  gload16(gb0, lds + ob0);
  gload16(gb1, lds + ob1);
  ga0 += BK; ga1 += BK; gb0 += BK; gb1 += BK;
  __syncthreads();

  int cur = 0;
  for (int ks = 0; ks < ksteps; ++ks) {
    const int nxt = cur ^ 1;
    if (ks + 1 < ksteps) {
      bf16_t* nb = lds + nxt * TILE_ELEMS;
      gload16(ga0, nb + oa0);
      gload16(ga1, nb + oa1);
      gload16(gb0, nb + ob0);
      gload16(gb1, nb + ob1);
      ga0 += BK; ga1 += BK; gb0 += BK; gb1 += BK;
    }
    const bf16_t* cb = lds + cur * TILE_ELEMS;
    bf16x8 af[4], bfv[4];
#pragma unroll
    for (int m = 0; m < 4; ++m)
      af[m] = *(const bf16x8*)(cb + (wr + m * 16 + fr) * BK + kg * 8);
#pragma unroll
    for (int n = 0; n < 4; ++n)
      bfv[n] = *(const bf16x8*)(cb + BM * BK + (wc + n * 16 + fr) * BK + kg * 8);
#pragma unroll
    for (int m = 0; m < 4; ++m)
#pragma unroll
      for (int n = 0; n < 4; ++n)
        acc[m][n] = __builtin_amdgcn_mfma_f32_16x16x32_bf16(af[m], bfv[n],
                                                            acc[m][n], 0, 0, 0);
    __syncthreads();
    cur = nxt;
  }
}

// ===========================================================================
// NEW: 128x256 / BK=64 / 8-wave (2Mx4N) 4-phase counted-vmcnt mainloop (QKV).
// LDS: 2 bufs x (A 16KB + B 32KB) = 96KB -> 1 blk/CU; grid must be 256-balanced.
// Chunked slot layout: region(64 rows)=8KB; elem = rg*1024 + c8*128 + fr*8
//   (row = rg*16+fr, col = c8*8) -> all ds_read_b128 64-lane contiguous, 0 conf.
// Liveness: B-frags all read in p0 -> B(t+2) issued p1/p2 into cur buf;
//           A-frag m read in phase m -> A(t+1) issued at p0 into other buf.
// Boundary (t<nk-1, after p3): queue = B(t+1)x4, A(t+1)x2, B(t+2)x4
//   -> vmcnt(4) drains tile t+1; tail (no B(t+2)): vmcnt(0).
// ===========================================================================
__device__ __forceinline__ void gemm8ph(
    const bf16_t* __restrict__ A, int lda,
    const bf16_t* __restrict__ B, int ldb,
    int nk, bf16_t* lds, f32x4 acc[4][4]) {
  const int tid = threadIdx.x;               // 512
  const int wid = tid >> 6, lane = tid & 63;
  const int wm = wid >> 2, wn = wid & 3;
  const int fr = lane & 15, kg = (lane >> 4) & 3;
  const int srow = ((tid >> 7) << 4) | (tid & 15);  // region-local row
  const int scol = ((tid >> 4) & 7) << 3;           // col elems
  const bf16_t* pA = A + (size_t)srow * lda + scol;
  const bf16_t* pB = B + (size_t)srow * ldb + scol;
  const int dst = tid * 8;                          // elems within 8KB region

  auto stgA = [&](int t, int j) {                   // j in {0,1}
    gload16(pA + (size_t)(j * 64) * lda + t * 64,
            lds + (t & 1) * 24576 + j * 4096 + dst);
  };
  auto stgB = [&](int t, int j) {                   // j in {0..3}
    gload16(pB + (size_t)(j * 64) * ldb + t * 64,
            lds + (t & 1) * 24576 + 8192 + j * 4096 + dst);
  };

  // prologue: B(0) A(0) fully; B(1); drain tile0 (oldest 6)
  stgB(0, 0); stgB(0, 1); stgB(0, 2); stgB(0, 3);
  stgA(0, 0); stgA(0, 1);
  if (nk > 1) {
    stgB(1, 0); stgB(1, 1); stgB(1, 2); stgB(1, 3);
    asm volatile("s_waitcnt vmcnt(4)" ::: "memory");
  } else {
    asm volatile("s_waitcnt vmcnt(0)" ::: "memory");
  }
  wgbar();

  const int ro = kg * 128 + fr * 8;
  for (int t = 0; t < nk; ++t) {
    const bf16_t* bb = lds + (t & 1) * 24576;
    const bf16_t* as = bb + wm * 4096;          // wave's A region (4 rgs)
    const bf16_t* bs = bb + 8192 + wn * 4096;   // wave's B region (4 rgs)
    bf16x8 bF[4][2], aF[2];
    // ---- p0: all B frags + A row 0; issue A(t+1)
#pragma unroll
    for (int n = 0; n < 4; ++n) {
      bF[n][0] = *(const bf16x8*)(bs + n * 1024 + ro);
      bF[n][1] = *(const bf16x8*)(bs + n * 1024 + 512 + ro);
    }
    aF[0] = *(const bf16x8*)(as + ro);
    aF[1] = *(const bf16x8*)(as + 512 + ro);
    if (t + 1 < nk) { stgA(t + 1, 0); stgA(t + 1, 1); }
    wgbar();
    __builtin_amdgcn_s_setprio(1);
#pragma unroll
    for (int n = 0; n < 4; ++n) {
      acc[0][n] = __builtin_amdgcn_mfma_f32_16x16x32_bf16(aF[0], bF[n][0], acc[0][n], 0, 0, 0);
      acc[0][n] = __builtin_amdgcn_mfma_f32_16x16x32_bf16(aF[1], bF[n][1], acc[0][n], 0, 0, 0);
    }
    __builtin_amdgcn_s_setprio(0);
    asm volatile("s_waitcnt lgkmcnt(0)" ::: "memory");
    wgbar();
    // ---- p1: A row 1; issue B(t+2) 0,1
    aF[0] = *(const bf16x8*)(as + 1024 + ro);
    aF[1] = *(const bf16x8*)(as + 1024 + 512 + ro);
    if (t + 2 < nk) { stgB(t + 2, 0); stgB(t + 2, 1); }
    wgbar();
    __builtin_amdgcn_s_setprio(1);
#pragma unroll
    for (int n = 0; n < 4; ++n) {
      acc[1][n] = __builtin_amdgcn_mfma_f32_16x16x32_bf16(aF[0], bF[n][0], acc[1][n], 0, 0, 0);
      acc[1][n] = __builtin_amdgcn_mfma_f32_16x16x32_bf16(aF[1], bF[n][1], acc[1][n], 0, 0, 0);
    }
    __builtin_amdgcn_s_setprio(0);
    asm volatile("s_waitcnt lgkmcnt(0)" ::: "memory");
    wgbar();
    // ---- p2: A row 2; issue B(t+2) 2,3
    aF[0] = *(const bf16x8*)(as + 2048 + ro);
    aF[1] = *(const bf16x8*)(as + 2048 + 512 + ro);
    if (t + 2 < nk) { stgB(t + 2, 2); stgB(t + 2, 3); }
    wgbar();
    __builtin_amdgcn_s_setprio(1);
#pragma unroll
    for (int n = 0; n < 4; ++n) {
      acc[2][n] = __builtin_amdgcn_mfma_f32_16x16x32_bf16(aF[0], bF[n][0], acc[2][n], 0, 0, 0);
      acc[2][n] = __builtin_amdgcn_mfma_f32_16x16x32_bf16(aF[1], bF[n][1], acc[2][n], 0, 0, 0);
    }
    __builtin_amdgcn_s_setprio(0);
    asm volatile("s_waitcnt lgkmcnt(0)" ::: "memory");
    wgbar();
    // ---- p3: A row 3; boundary drain
    aF[0] = *(const bf16x8*)(as + 3072 + ro);
    aF[1] = *(const bf16x8*)(as + 3072 + 512 + ro);
    wgbar();
    __builtin_amdgcn_s_setprio(1);
#pragma unroll
    for (int n = 0; n < 4; ++n) {
      acc[3][n] = __builtin_amdgcn_mfma_f32_16x16x32_bf16(aF[0], bF[n][0], acc[3][n], 0, 0, 0);
      acc[3][n] = __builtin_amdgcn_mfma_f32_16x16x32_bf16(aF[1], bF[n][1], acc[3][n], 0, 0, 0);
    }
    __builtin_amdgcn_s_setprio(0);
    asm volatile("s_waitcnt lgkmcnt(0)" ::: "memory");
    if (t < nk - 1) {
      if (t + 2 < nk) asm volatile("s_waitcnt vmcnt(4)" ::: "memory");
      else            asm volatile("s_waitcnt vmcnt(0)" ::: "memory");
    }
    wgbar();
  }
}

// C/D frag (16x16x32, verified m89/m91): col = lane&15, row = (lane>>4)*4 + i.

// ------------- fused QKV: 128x256, 8ph, grid 768 = 3 balanced rounds --------
__global__ __launch_bounds__(512)
void k_qkv8(const bf16_t* __restrict__ A, const bf16_t* __restrict__ WT,
            const float* __restrict__ bq, const float* __restrict__ bk,
            const float* __restrict__ bv, bf16_t* __restrict__ Out) {
  __shared__ bf16_t lds[49152];                  // 96KB
  const int id = blockIdx.x;                     // 768 = 64 mb x 12 nb
  const int swz = (id & 7) * 96 + (id >> 3);     // XCD-chunked (768%8==0)
  const int mb = swz / 12, nb = swz % 12;
  const int which = nb >> 2;                     // 0=Q,1=K,2=V
  const int m0 = mb * 128, n0 = (nb & 3) * 256;
  f32x4 acc[4][4] = {};
  gemm8ph(A + (size_t)m0 * kD, kD,
          WT + (size_t)which * kD * kD + (size_t)n0 * kD, kD,
          kD / 64, lds, acc);
  const float* bias = which == 0 ? bq : which == 1 ? bk : bv;
  const int lane = threadIdx.x & 63, wid = threadIdx.x >> 6;
  const int wm = wid >> 2, wn = wid & 3, fr = lane & 15, kgr = lane >> 4;
  if (which < 2) {
    bf16_t* C = Out + (size_t)which * kB * kS * kD;
#pragma unroll
    for (int n = 0; n < 4; ++n) {
      const int col = n0 + wn * 64 + n * 16 + fr;
      const float bvv = bias[col];
#pragma unroll
      for (int m = 0; m < 4; ++m)
#pragma unroll
        for (int i = 0; i < 4; ++i) {
          const int row = m0 + wm * 64 + m * 16 + kgr * 4 + i;
          C[(size_t)row * kD + col] = (bf16_t)(acc[m][n][i] + bvv);
        }
    }
  } else {  // V -> VT[b][d][s]
    bf16_t* VT = Out + (size_t)2 * kB * kS * kD;
#pragma unroll
    for (int n = 0; n < 4; ++n) {
      const int col = n0 + wn * 64 + n * 16 + fr;
      const float bvv = bias[col];
#pragma unroll
      for (int m = 0; m < 4; ++m)
#pragma unroll
        for (int i = 0; i < 4; ++i) {
          const int row = m0 + wm * 64 + m * 16 + kgr * 4 + i;
          const int b = row >> 11, s = row & (kS - 1);
          VT[((size_t)b * kD + col) * kS + s] = (bf16_t)(acc[m][n][i] + bvv);
        }
    }
  }
}

// ------------- scores = Q*K^T/32: R2-exact triangular 128x128 ---------------
__global__ __launch_bounds__(256)
void k_gemm_scores(const bf16_t* __restrict__ Q, const bf16_t* __restrict__ K,
                   float* __restrict__ Sc) {
  const int t = blockIdx.x, b = blockIdx.y;
  int by = (int)((sqrtf(8.f * t + 1.f) - 1.f) * 0.5f);
  while ((by + 1) * (by + 2) / 2 <= t) ++by;
  while (by * (by + 1) / 2 > t) --by;
  const int bx = t - by * (by + 1) / 2;
  __shared__ bf16_t lds[2 * TILE_ELEMS];
  const int m0 = by * BM, n0 = bx * BN;
  f32x4 acc[4][4] = {};
  gemm_mainloop(Q + (size_t)b * kS * kD + (size_t)m0 * kD, kD,
                K + (size_t)b * kS * kD + (size_t)n0 * kD, kD, kD / BK, lds, acc);
  float* Sb = Sc + (size_t)b * kS * kS;
  const int tid = threadIdx.x, w = tid >> 6, lane = tid & 63;
  const int wr = (w >> 1) << 6, wc = (w & 1) << 6, fr = lane & 15, kg = lane >> 4;
#pragma unroll
  for (int m = 0; m < 4; ++m)
#pragma unroll
    for (int n = 0; n < 4; ++n)
#pragma unroll
      for (int i = 0; i < 4; ++i) {
        const int row = m0 + wr + m * 16 + kg * 4 + i;
        const int col = n0 + wc + n * 16 + fr;
        Sb[(size_t)row * kS + col] = acc[m][n][i] * 0.03125f;
      }
}

// ------------- row softmax (causal): R2-exact -------------------------------
__global__ __launch_bounds__(256)
void k_softmax(float* __restrict__ P, bf16_t* __restrict__ Pb) {
  const int row = blockIdx.x;
  const int q = row & (kS - 1);
  float* p = P + (size_t)row * kS;
  bf16_t* pb = Pb + (size_t)row * kS;
  const int L = q + 1;
  __shared__ float buf[kS];
  __shared__ float red[8];
  const int tid = threadIdx.x;
  float4* b4 = (float4*)buf;
  const float4* p4 = (const float4*)p;
  if (tid * 4 < L) b4[tid] = p4[tid];
  if (1024 + tid * 4 < L) b4[tid + 256] = p4[tid + 256];
  __syncthreads();
  float mx = -1e30f;
  for (int k = tid; k < L; k += 256) mx = fmaxf(mx, buf[k]);
#pragma unroll
  for (int s2 = 32; s2 >= 1; s2 >>= 1) mx = fmaxf(mx, __shfl_xor(mx, s2));
  if ((tid & 63) == 0) red[tid >> 6] = mx;
  __syncthreads();
  mx = fmaxf(fmaxf(red[0], red[1]), fmaxf(red[2], red[3]));
  float sm = 0.f;
  for (int k = tid; k < L; k += 256) {
    const float e = __expf(buf[k] - mx);
    buf[k] = e;
    sm += e;
  }
#pragma unroll
  for (int s2 = 32; s2 >= 1; s2 >>= 1) sm += __shfl_xor(sm, s2);
  if ((tid & 63) == 0) red[4 + (tid >> 6)] = sm;
  __syncthreads();
  const float inv = 1.f / (red[4] + red[5] + red[6] + red[7]);
  for (int k = tid; k < L; k += 256) {
    const float v = buf[k] * inv;
    p[k] = v;
    pb[k] = (bf16_t)v;
  }
  for (int k = L + tid; k < kS; k += 256) {
    p[k] = 0.f;
    pb[k] = (bf16_t)0.f;
  }
}

// ------------- attn_out = P*V: R2-exact (LPT, causal K-limit) ---------------
__global__ __launch_bounds__(256)
void k_gemm_pv(const bf16_t* __restrict__ P, const bf16_t* __restrict__ VT,
               bf16_t* __restrict__ AO) {
  const int bx = blockIdx.x, b = blockIdx.z;
  const int by = (int)gridDim.y - 1 - (int)blockIdx.y;
  __shared__ bf16_t lds[2 * TILE_ELEMS];
  const int m0 = by * BM, n0 = bx * BN;
  const int ksteps = (m0 + BM) / BK;
  f32x4 acc[4][4] = {};
  gemm_mainloop(P + (size_t)b * kS * kS + (size_t)m0 * kS, kS,
                VT + (size_t)b * kD * kS + (size_t)n0 * kS, kS, ksteps, lds, acc);
  bf16_t* AOb = AO + (size_t)b * kS * kD;
  const int tid = threadIdx.x, w = tid >> 6, lane = tid & 63;
  const int wr = (w >> 1) << 6, wc = (w & 1) << 6, fr = lane & 15, kg = lane >> 4;
#pragma unroll
  for (int m = 0; m < 4; ++m)
#pragma unroll
    for (int n = 0; n < 4; ++n)
#pragma unroll
      for (int i = 0; i < 4; ++i) {
        const int row = m0 + wr + m * 16 + kg * 4 + i;
        const int col = n0 + wc + n * 16 + fr;
        AOb[(size_t)row * kD + col] = (bf16_t)acc[m][n][i];
      }
}

// ------------- out = AO*Wo^T + bo: R2-exact ---------------------------------
__global__ __launch_bounds__(256)
void k_gemm_out(const bf16_t* __restrict__ A, const bf16_t* __restrict__ Bw,
                const float* __restrict__ bias, float* __restrict__ C) {
  __shared__ bf16_t lds[2 * TILE_ELEMS];
  const int m0 = blockIdx.y * BM, n0 = blockIdx.x * BN;
  f32x4 acc[4][4] = {};
  gemm_mainloop(A + (size_t)m0 * kD, kD, Bw + (size_t)n0 * kD, kD, kD / BK, lds, acc);
  const int tid = threadIdx.x, w = tid >> 6, lane = tid & 63;
  const int wr = (w >> 1) << 6, wc = (w & 1) << 6, fr = lane & 15, kg = lane >> 4;
#pragma unroll
  for (int n = 0; n < 4; ++n) {
    const int col = n0 + wc + n * 16 + fr;
    const float bv = bias[col];
#pragma unroll
    for (int m = 0; m < 4; ++m)
#pragma unroll
      for (int i = 0; i < 4; ++i) {
        const int row = m0 + wr + m * 16 + kg * 4 + i;
        C[(size_t)row * kD + col] = acc[m][n][i] + bv;
      }
  }
}

// ------------- fused prep: z<4 weight transpose->bf16, z==4 x->bf16 ---------
__global__ __launch_bounds__(256)
void k_prep(const float* __restrict__ X, bf16_t* __restrict__ Y,
            const float* __restrict__ W0, const float* __restrict__ W1,
            const float* __restrict__ W2, const float* __restrict__ W3,
            bf16_t* __restrict__ T0, bf16_t* __restrict__ T1,
            bf16_t* __restrict__ T2, bf16_t* __restrict__ T3) {
  const int tx = threadIdx.x & 31, ty = threadIdx.x >> 5;
  if (blockIdx.z == 4) {
    const size_t n4 = (size_t)kB * kS * kD / 4;
    size_t i = ((size_t)blockIdx.y * 32 + blockIdx.x) * 256 + threadIdx.x;
    const size_t stride = (size_t)1024 * 256;
    const float4* X4 = (const float4*)X;
    bf16x4* Y4 = (bf16x4*)Y;
    for (; i < n4; i += stride) {
      const float4 v = X4[i];
      bf16x4 o = {(bf16_t)v.x, (bf16_t)v.y, (bf16_t)v.z, (bf16_t)v.w};
      Y4[i] = o;
    }
    return;
  }
  const float* W = blockIdx.z == 0 ? W0 : blockIdx.z == 1 ? W1 : blockIdx.z == 2 ? W2 : W3;
  bf16_t* T = blockIdx.z == 0 ? T0 : blockIdx.z == 1 ? T1 : blockIdx.z == 2 ? T2 : T3;
  __shared__ float t[32][33];
  const int x0 = blockIdx.x * 32, y0 = blockIdx.y * 32;
#pragma unroll
  for (int j = 0; j < 4; ++j)
    t[ty + 8 * j][tx] = W[(size_t)(y0 + ty + 8 * j) * kD + x0 + tx];
  __syncthreads();
#pragma unroll
  for (int j = 0; j < 4; ++j)
    T[(size_t)(x0 + ty + 8 * j) * kD + y0 + tx] = (bf16_t)t[tx][ty + 8 * j];
}

extern "C" void kernel_launch(void* const* d_in, const int* in_sizes, int n_in,
                              void* d_out, int out_size, void* d_ws, size_t ws_size,
                              hipStream_t stream) {
  (void)in_sizes; (void)n_in; (void)out_size; (void)ws_size;
  const float* x  = (const float*)d_in[0];
  // d_in[1] = mask: tril(ones) by construction -> causality hardcoded
  const float* Wq = (const float*)d_in[2];
  const float* bq = (const float*)d_in[3];
  const float* Wk = (const float*)d_in[4];
  const float* bk = (const float*)d_in[5];
  const float* Wv = (const float*)d_in[6];
  const float* bv = (const float*)d_in[7];
  const float* Wo = (const float*)d_in[8];
  const float* bo = (const float*)d_in[9];

  float* out  = (float*)d_out;                       // [4,2048,1024] fp32
  float* Pout = out + (size_t)kB * kS * kD;          // [4,2048,2048] fp32

  bf16_t* WqT = (bf16_t*)d_ws;                       // [3][1024][1024] packed + WoT
  bf16_t* WkT = WqT + (size_t)kD * kD;
  bf16_t* WvT = WkT + (size_t)kD * kD;
  bf16_t* WoT = WvT + (size_t)kD * kD;
  bf16_t* Qb  = WoT + (size_t)kD * kD;               // Q,K row-major; VT transposed
  bf16_t* Kb  = Qb + (size_t)kB * kS * kD;
  bf16_t* VTb = Kb + (size_t)kB * kS * kD;
  bf16_t* Pb  = VTb + (size_t)kB * kS * kD;
  bf16_t* AOb = Pb + (size_t)kB * kS * kS;
  bf16_t* xb  = AOb + (size_t)kB * kS * kD;

  k_prep<<<dim3(32, 32, 5), 256, 0, stream>>>(x, xb, Wq, Wk, Wv, Wo,
                                              WqT, WkT, WvT, WoT);
  k_qkv8<<<768, 512, 0, stream>>>(xb, WqT, bq, bk, bv, Qb);
  k_gemm_scores<<<dim3(136, kB), 256, 0, stream>>>(Qb, Kb, Pout);
  k_softmax<<<kB * kS, 256, 0, stream>>>(Pout, Pb);
  k_gemm_pv<<<dim3(8, 16, kB), 256, 0, stream>>>(Pb, VTb, AOb);
  k_gemm_out<<<dim3(8, 64), 256, 0, stream>>>(AOb, WoT, bo, out);
}

// Round 6
// 220.883 us; speedup vs baseline: 1.2362x; 1.0604x over previous
//
#include <hip/hip_runtime.h>
#include <cstdint>
#include <cstddef>
#include <cmath>

typedef __bf16 bf16_t;
typedef bf16_t bf16x8 __attribute__((ext_vector_type(8)));
typedef bf16_t bf16x4 __attribute__((ext_vector_type(4)));
typedef float f32x4 __attribute__((ext_vector_type(4)));

constexpr int kB = 4;
constexpr int kS = 2048;
constexpr int kD = 1024;
constexpr int BM = 128, BN = 128, BK = 32;
constexpr int TILE_ELEMS = (BM + BN) * BK;   // 16KB per buffer

typedef __attribute__((address_space(1))) void as1void;
typedef __attribute__((address_space(3))) void as3void;

__device__ __forceinline__ void gload16(const void* g, void* l) {
  __builtin_amdgcn_global_load_lds((as1void*)g, (as3void*)l, 16, 0, 0);
}

__device__ __forceinline__ void wgbar() {
  asm volatile("" ::: "memory");
  __builtin_amdgcn_s_barrier();
  asm volatile("" ::: "memory");
}

// ===========================================================================
// R2-proven 2-phase mainloop (128x128, 4 waves, linear LDS). Untouched.
// ===========================================================================
__device__ __forceinline__ void gemm_mainloop(
    const bf16_t* __restrict__ A, int lda,
    const bf16_t* __restrict__ B, int ldb,
    int ksteps, bf16_t* lds, f32x4 acc[4][4]) {
  const int tid = threadIdx.x;
  const int w = tid >> 6, lane = tid & 63;
  const int srow = lane >> 2;
  const int scol = (lane & 3) << 3;
  const int wr = (w >> 1) << 6, wc = (w & 1) << 6;
  const int fr = lane & 15, kg = lane >> 4;

  const bf16_t* ga0 = A + (size_t)(w * 16 + srow) * lda + scol;
  const bf16_t* ga1 = A + (size_t)(64 + w * 16 + srow) * lda + scol;
  const bf16_t* gb0 = B + (size_t)(w * 16 + srow) * ldb + scol;
  const bf16_t* gb1 = B + (size_t)(64 + w * 16 + srow) * ldb + scol;
  const int oa0 = (w * 16) * BK;
  const int oa1 = (64 + w * 16) * BK;
  const int ob0 = BM * BK + (w * 16) * BK;
  const int ob1 = BM * BK + (64 + w * 16) * BK;

  gload16(ga0, lds + oa0);
  gload16(ga1, lds + oa1);
  gload16(gb0, lds + ob0);
  gload16(gb1, lds + ob1);
  ga0 += BK; ga1 += BK; gb0 += BK; gb1 += BK;
  __syncthreads();

  int cur = 0;
  for (int ks = 0; ks < ksteps; ++ks) {
    const int nxt = cur ^ 1;
    if (ks + 1 < ksteps) {
      bf16_t* nb = lds + nxt * TILE_ELEMS;
      gload16(ga0, nb + oa0);
      gload16(ga1, nb + oa1);
      gload16(gb0, nb + ob0);
      gload16(gb1, nb + ob1);
      ga0 += BK; ga1 += BK; gb0 += BK; gb1 += BK;
    }
    const bf16_t* cb = lds + cur * TILE_ELEMS;
    bf16x8 af[4], bfv[4];
#pragma unroll
    for (int m = 0; m < 4; ++m)
      af[m] = *(const bf16x8*)(cb + (wr + m * 16 + fr) * BK + kg * 8);
#pragma unroll
    for (int n = 0; n < 4; ++n)
      bfv[n] = *(const bf16x8*)(cb + BM * BK + (wc + n * 16 + fr) * BK + kg * 8);
#pragma unroll
    for (int m = 0; m < 4; ++m)
#pragma unroll
      for (int n = 0; n < 4; ++n)
        acc[m][n] = __builtin_amdgcn_mfma_f32_16x16x32_bf16(af[m], bfv[n],
                                                            acc[m][n], 0, 0, 0);
    __syncthreads();
    cur = nxt;
  }
}

// ===========================================================================
// R3-proven 256x256 / BK=64 / 8-wave / 512-thread 8-phase mainloop. Verbatim.
// Chunked conflict-free LDS; counted vmcnt(6); setprio around MFMA clusters.
// ===========================================================================
__device__ __forceinline__ void gemm256_loop(
    const bf16_t* __restrict__ A, int lda,
    const bf16_t* __restrict__ B, int ldb,
    int nk, bf16_t* lds, f32x4 acc[8][4]) {
  const int tid = threadIdx.x;
  const int wid = tid >> 6, lane = tid & 63;
  const int wm = wid >> 2, wn = wid & 3;
  const int fr = lane & 15, kg = (lane >> 4) & 3;
  const int s_row = ((tid >> 7) << 4) | (tid & 15);
  const int s_col = ((tid >> 4) & 7) << 3;
  const bf16_t* pA = A + (size_t)s_row * lda + s_col;
  const bf16_t* pB = B + (size_t)s_row * ldb + s_col;
  const int ldst = wid << 9;

  auto stg = [&](int tt, int op, int h, int j) {
    const bf16_t* g = (op ? pB : pA) + (size_t)(h * 128 + j * 64) * (op ? ldb : lda)
                      + (size_t)tt * 64;
    bf16_t* d = lds + (((tt & 1) * 4 + op * 2 + h) * 8192) + j * 4096 + ldst;
    gload16(g, d);
  };

#pragma unroll
  for (int h = 0; h < 2; ++h)
#pragma unroll
    for (int j = 0; j < 2; ++j) { stg(0, 0, h, j); stg(0, 1, h, j); }
  stg(1, 1, 0, 0); stg(1, 1, 0, 1); stg(1, 1, 1, 0); stg(1, 1, 1, 1);
  stg(1, 0, 0, 0); stg(1, 0, 1, 0);
  asm volatile("s_waitcnt vmcnt(6)" ::: "memory");
  wgbar();

  const int arow = kg * 128 + fr * 8;
  for (int t = 0; t < nk; ++t) {
    const bf16_t* sb = lds + (t & 1) * 32768;
    const bf16_t* aslot = sb + wm * 8192;
    const bf16_t* bslot = sb + (2 + (wn >> 1)) * 8192 + (wn & 1) * 4096;
    bf16x8 bF[4][2];
#pragma unroll
    for (int q = 0; q < 4; ++q) {
      bf16x8 aF[2][2];
#pragma unroll
      for (int mi = 0; mi < 2; ++mi)
#pragma unroll
        for (int ks = 0; ks < 2; ++ks)
          aF[mi][ks] = *(const bf16x8*)(aslot + (2 * q + mi) * 1024 + ks * 512 + arow);
      if (q == 0) {
#pragma unroll
        for (int n = 0; n < 4; ++n)
#pragma unroll
          for (int ks = 0; ks < 2; ++ks)
            bF[n][ks] = *(const bf16x8*)(bslot + n * 1024 + ks * 512 + arow);
      }
      if (q == 0)      { if (t + 1 <= nk - 1) { stg(t + 1, 0, 0, 1); stg(t + 1, 0, 1, 1); } }
      else if (q == 1) { if (t + 2 <= nk - 1) { stg(t + 2, 1, 0, 0); stg(t + 2, 1, 0, 1); } }
      else if (q == 2) { if (t + 2 <= nk - 1) { stg(t + 2, 1, 1, 0); stg(t + 2, 1, 1, 1); } }
      else             { if (t + 2 <= nk - 1) { stg(t + 2, 0, 0, 0); stg(t + 2, 0, 1, 0); } }
      wgbar();
      __builtin_amdgcn_s_setprio(1);
#pragma unroll
      for (int mi = 0; mi < 2; ++mi)
#pragma unroll
        for (int n = 0; n < 4; ++n)
#pragma unroll
          for (int ks = 0; ks < 2; ++ks)
            acc[2 * q + mi][n] = __builtin_amdgcn_mfma_f32_16x16x32_bf16(
                aF[mi][ks], bF[n][ks], acc[2 * q + mi][n], 0, 0, 0);
      __builtin_amdgcn_s_setprio(0);
      asm volatile("s_waitcnt lgkmcnt(0)" ::: "memory");
      if (q == 3 && t < nk - 1) {
        if (t + 2 <= nk - 1) asm volatile("s_waitcnt vmcnt(6)" ::: "memory");
        else                 asm volatile("s_waitcnt vmcnt(0)" ::: "memory");
      }
      wgbar();
    }
  }
}

// C/D frag (16x16x32, verified m89/m91): col = lane&15, row = (lane>>4)*4 + i.

// ------------- QK projection: 256^2 8-phase, grid EXACTLY 256 (1 round) -----
// N-space = 2048 cols of packed [WqT; WkT]. col<1024 -> Q, else K.
__global__ __launch_bounds__(512, 2)
void k_qk256(const bf16_t* __restrict__ A, const bf16_t* __restrict__ WT,
             const float* __restrict__ bq, const float* __restrict__ bk,
             bf16_t* __restrict__ Qb, bf16_t* __restrict__ Kb) {
  __shared__ bf16_t lds[65536];
  const int id = blockIdx.x;                     // 256 = 32 mb x 8 nb
  const int swz = (id & 7) * 32 + (id >> 3);     // XCD-chunked (256%8==0)
  const int mb = swz >> 3, nb = swz & 7;
  const int m0 = mb * 256, n0 = nb * 256;
  f32x4 acc[8][4] = {};
  gemm256_loop(A + (size_t)m0 * kD, kD, WT + (size_t)n0 * kD, kD,
               kD / 64, lds, acc);
  const int lane = threadIdx.x & 63, wid = threadIdx.x >> 6;
  const int wm = wid >> 2, wn = wid & 3, fr = lane & 15, kgr = lane >> 4;
  const int which = n0 >> 10;                    // 256-tiles don't straddle 1024
  bf16_t* C = which == 0 ? Qb : Kb;
  const float* bias = which == 0 ? bq : bk;
#pragma unroll
  for (int n = 0; n < 4; ++n) {
    const int col = (n0 & 1023) + wn * 64 + n * 16 + fr;
    const float bvv = bias[col];
#pragma unroll
    for (int m = 0; m < 8; ++m)
#pragma unroll
      for (int i = 0; i < 4; ++i) {
        const int row = m0 + wm * 128 + m * 16 + kgr * 4 + i;
        C[(size_t)row * kD + col] = (bf16_t)(acc[m][n][i] + bvv);
      }
  }
}

// ------------- V projection: 128^2 2-phase, grid 512 (=2x256), VT out -------
__global__ __launch_bounds__(256)
void k_v128(const bf16_t* __restrict__ A, const bf16_t* __restrict__ Bw,
            const float* __restrict__ bias, bf16_t* __restrict__ VT) {
  __shared__ bf16_t lds[2 * TILE_ELEMS];
  const int id = blockIdx.x;                     // 512 = 64 mb x 8 nb
  const int swz = (id & 7) * 64 + (id >> 3);
  const int m0 = (swz >> 3) * BM, n0 = (swz & 7) * BN;
  f32x4 acc[4][4] = {};
  gemm_mainloop(A + (size_t)m0 * kD, kD, Bw + (size_t)n0 * kD, kD, kD / BK, lds, acc);
  const int tid = threadIdx.x, w = tid >> 6, lane = tid & 63;
  const int wr = (w >> 1) << 6, wc = (w & 1) << 6, fr = lane & 15, kg = lane >> 4;
#pragma unroll
  for (int n = 0; n < 4; ++n) {
    const int col = n0 + wc + n * 16 + fr;
    const float bvv = bias[col];
#pragma unroll
    for (int m = 0; m < 4; ++m)
#pragma unroll
      for (int i = 0; i < 4; ++i) {
        const int row = m0 + wr + m * 16 + kg * 4 + i;
        const int b = row >> 11, s = row & (kS - 1);
        VT[((size_t)b * kD + col) * kS + s] = (bf16_t)(acc[m][n][i] + bvv);
      }
  }
}

// ------------- scores = Q*K^T/32: R2-exact triangular 128x128 ---------------
__global__ __launch_bounds__(256)
void k_gemm_scores(const bf16_t* __restrict__ Q, const bf16_t* __restrict__ K,
                   float* __restrict__ Sc) {
  const int t = blockIdx.x, b = blockIdx.y;
  int by = (int)((sqrtf(8.f * t + 1.f) - 1.f) * 0.5f);
  while ((by + 1) * (by + 2) / 2 <= t) ++by;
  while (by * (by + 1) / 2 > t) --by;
  const int bx = t - by * (by + 1) / 2;
  __shared__ bf16_t lds[2 * TILE_ELEMS];
  const int m0 = by * BM, n0 = bx * BN;
  f32x4 acc[4][4] = {};
  gemm_mainloop(Q + (size_t)b * kS * kD + (size_t)m0 * kD, kD,
                K + (size_t)b * kS * kD + (size_t)n0 * kD, kD, kD / BK, lds, acc);
  float* Sb = Sc + (size_t)b * kS * kS;
  const int tid = threadIdx.x, w = tid >> 6, lane = tid & 63;
  const int wr = (w >> 1) << 6, wc = (w & 1) << 6, fr = lane & 15, kg = lane >> 4;
#pragma unroll
  for (int m = 0; m < 4; ++m)
#pragma unroll
    for (int n = 0; n < 4; ++n)
#pragma unroll
      for (int i = 0; i < 4; ++i) {
        const int row = m0 + wr + m * 16 + kg * 4 + i;
        const int col = n0 + wc + n * 16 + fr;
        Sb[(size_t)row * kS + col] = acc[m][n][i] * 0.03125f;
      }
}

// ------------- row softmax (causal): R2-exact -------------------------------
__global__ __launch_bounds__(256)
void k_softmax(float* __restrict__ P, bf16_t* __restrict__ Pb) {
  const int row = blockIdx.x;
  const int q = row & (kS - 1);
  float* p = P + (size_t)row * kS;
  bf16_t* pb = Pb + (size_t)row * kS;
  const int L = q + 1;
  __shared__ float buf[kS];
  __shared__ float red[8];
  const int tid = threadIdx.x;
  float4* b4 = (float4*)buf;
  const float4* p4 = (const float4*)p;
  if (tid * 4 < L) b4[tid] = p4[tid];
  if (1024 + tid * 4 < L) b4[tid + 256] = p4[tid + 256];
  __syncthreads();
  float mx = -1e30f;
  for (int k = tid; k < L; k += 256) mx = fmaxf(mx, buf[k]);
#pragma unroll
  for (int s2 = 32; s2 >= 1; s2 >>= 1) mx = fmaxf(mx, __shfl_xor(mx, s2));
  if ((tid & 63) == 0) red[tid >> 6] = mx;
  __syncthreads();
  mx = fmaxf(fmaxf(red[0], red[1]), fmaxf(red[2], red[3]));
  float sm = 0.f;
  for (int k = tid; k < L; k += 256) {
    const float e = __expf(buf[k] - mx);
    buf[k] = e;
    sm += e;
  }
#pragma unroll
  for (int s2 = 32; s2 >= 1; s2 >>= 1) sm += __shfl_xor(sm, s2);
  if ((tid & 63) == 0) red[4 + (tid >> 6)] = sm;
  __syncthreads();
  const float inv = 1.f / (red[4] + red[5] + red[6] + red[7]);
  for (int k = tid; k < L; k += 256) {
    const float v = buf[k] * inv;
    p[k] = v;
    pb[k] = (bf16_t)v;
  }
  for (int k = L + tid; k < kS; k += 256) {
    p[k] = 0.f;
    pb[k] = (bf16_t)0.f;
  }
}

// ------------- attn_out = P*V: R2-exact (LPT, causal K-limit) ---------------
__global__ __launch_bounds__(256)
void k_gemm_pv(const bf16_t* __restrict__ P, const bf16_t* __restrict__ VT,
               bf16_t* __restrict__ AO) {
  const int bx = blockIdx.x, b = blockIdx.z;
  const int by = (int)gridDim.y - 1 - (int)blockIdx.y;
  __shared__ bf16_t lds[2 * TILE_ELEMS];
  const int m0 = by * BM, n0 = bx * BN;
  const int ksteps = (m0 + BM) / BK;
  f32x4 acc[4][4] = {};
  gemm_mainloop(P + (size_t)b * kS * kS + (size_t)m0 * kS, kS,
                VT + (size_t)b * kD * kS + (size_t)n0 * kS, kS, ksteps, lds, acc);
  bf16_t* AOb = AO + (size_t)b * kS * kD;
  const int tid = threadIdx.x, w = tid >> 6, lane = tid & 63;
  const int wr = (w >> 1) << 6, wc = (w & 1) << 6, fr = lane & 15, kg = lane >> 4;
#pragma unroll
  for (int m = 0; m < 4; ++m)
#pragma unroll
    for (int n = 0; n < 4; ++n)
#pragma unroll
      for (int i = 0; i < 4; ++i) {
        const int row = m0 + wr + m * 16 + kg * 4 + i;
        const int col = n0 + wc + n * 16 + fr;
        AOb[(size_t)row * kD + col] = (bf16_t)acc[m][n][i];
      }
}

// ------------- out = AO*Wo^T + bo: R2-exact ---------------------------------
__global__ __launch_bounds__(256)
void k_gemm_out(const bf16_t* __restrict__ A, const bf16_t* __restrict__ Bw,
                const float* __restrict__ bias, float* __restrict__ C) {
  __shared__ bf16_t lds[2 * TILE_ELEMS];
  const int id = blockIdx.x;                     // 512 = 64 mb x 8 nb
  const int swz = (id & 7) * 64 + (id >> 3);
  const int m0 = (swz >> 3) * BM, n0 = (swz & 7) * BN;
  f32x4 acc[4][4] = {};
  gemm_mainloop(A + (size_t)m0 * kD, kD, Bw + (size_t)n0 * kD, kD, kD / BK, lds, acc);
  const int tid = threadIdx.x, w = tid >> 6, lane = tid & 63;
  const int wr = (w >> 1) << 6, wc = (w & 1) << 6, fr = lane & 15, kg = lane >> 4;
#pragma unroll
  for (int n = 0; n < 4; ++n) {
    const int col = n0 + wc + n * 16 + fr;
    const float bv = bias[col];
#pragma unroll
    for (int m = 0; m < 4; ++m)
#pragma unroll
      for (int i = 0; i < 4; ++i) {
        const int row = m0 + wr + m * 16 + kg * 4 + i;
        C[(size_t)row * kD + col] = acc[m][n][i] + bv;
      }
  }
}

// ------------- fused prep: z<4 weight transpose->bf16, z==4 x->bf16 ---------
__global__ __launch_bounds__(256)
void k_prep(const float* __restrict__ X, bf16_t* __restrict__ Y,
            const float* __restrict__ W0, const float* __restrict__ W1,
            const float* __restrict__ W2, const float* __restrict__ W3,
            bf16_t* __restrict__ T0, bf16_t* __restrict__ T1,
            bf16_t* __restrict__ T2, bf16_t* __restrict__ T3) {
  const int tx = threadIdx.x & 31, ty = threadIdx.x >> 5;
  if (blockIdx.z == 4) {
    const size_t n4 = (size_t)kB * kS * kD / 4;
    size_t i = ((size_t)blockIdx.y * 32 + blockIdx.x) * 256 + threadIdx.x;
    const size_t stride = (size_t)1024 * 256;
    const float4* X4 = (const float4*)X;
    bf16x4* Y4 = (bf16x4*)Y;
    for (; i < n4; i += stride) {
      const float4 v = X4[i];
      bf16x4 o = {(bf16_t)v.x, (bf16_t)v.y, (bf16_t)v.z, (bf16_t)v.w};
      Y4[i] = o;
    }
    return;
  }
  const float* W = blockIdx.z == 0 ? W0 : blockIdx.z == 1 ? W1 : blockIdx.z == 2 ? W2 : W3;
  bf16_t* T = blockIdx.z == 0 ? T0 : blockIdx.z == 1 ? T1 : blockIdx.z == 2 ? T2 : T3;
  __shared__ float t[32][33];
  const int x0 = blockIdx.x * 32, y0 = blockIdx.y * 32;
#pragma unroll
  for (int j = 0; j < 4; ++j)
    t[ty + 8 * j][tx] = W[(size_t)(y0 + ty + 8 * j) * kD + x0 + tx];
  __syncthreads();
#pragma unroll
  for (int j = 0; j < 4; ++j)
    T[(size_t)(x0 + ty + 8 * j) * kD + y0 + tx] = (bf16_t)t[tx][ty + 8 * j];
}

extern "C" void kernel_launch(void* const* d_in, const int* in_sizes, int n_in,
                              void* d_out, int out_size, void* d_ws, size_t ws_size,
                              hipStream_t stream) {
  (void)in_sizes; (void)n_in; (void)out_size; (void)ws_size;
  const float* x  = (const float*)d_in[0];
  // d_in[1] = mask: tril(ones) by construction -> causality hardcoded
  const float* Wq = (const float*)d_in[2];
  const float* bq = (const float*)d_in[3];
  const float* Wk = (const float*)d_in[4];
  const float* bk = (const float*)d_in[5];
  const float* Wv = (const float*)d_in[6];
  const float* bv = (const float*)d_in[7];
  const float* Wo = (const float*)d_in[8];
  const float* bo = (const float*)d_in[9];

  float* out  = (float*)d_out;                       // [4,2048,1024] fp32
  float* Pout = out + (size_t)kB * kS * kD;          // [4,2048,2048] fp32

  bf16_t* WqT = (bf16_t*)d_ws;                       // [WqT;WkT] packed for k_qk256
  bf16_t* WkT = WqT + (size_t)kD * kD;
  bf16_t* WvT = WkT + (size_t)kD * kD;
  bf16_t* WoT = WvT + (size_t)kD * kD;
  bf16_t* Qb  = WoT + (size_t)kD * kD;
  bf16_t* Kb  = Qb + (size_t)kB * kS * kD;
  bf16_t* VTb = Kb + (size_t)kB * kS * kD;
  bf16_t* Pb  = VTb + (size_t)kB * kS * kD;
  bf16_t* AOb = Pb + (size_t)kB * kS * kS;
  bf16_t* xb  = AOb + (size_t)kB * kS * kD;

  k_prep<<<dim3(32, 32, 5), 256, 0, stream>>>(x, xb, Wq, Wk, Wv, Wo,
                                              WqT, WkT, WvT, WoT);
  k_qk256<<<256, 512, 0, stream>>>(xb, WqT, bq, bk, Qb, Kb);
  k_v128<<<512, 256, 0, stream>>>(xb, WvT, bv, VTb);
  k_gemm_scores<<<dim3(136, kB), 256, 0, stream>>>(Qb, Kb, Pout);
  k_softmax<<<kB * kS, 256, 0, stream>>>(Pout, Pb);
  k_gemm_pv<<<dim3(8, 16, kB), 256, 0, stream>>>(Pb, VTb, AOb);
  k_gemm_out<<<512, 256, 0, stream>>>(AOb, WoT, bo, out);
}

// Round 7
// 209.614 us; speedup vs baseline: 1.3026x; 1.0538x over previous
//
#include <hip/hip_runtime.h>
#include <cstdint>
#include <cstddef>
#include <cmath>

typedef __bf16 bf16_t;
typedef bf16_t bf16x8 __attribute__((ext_vector_type(8)));
typedef bf16_t bf16x4 __attribute__((ext_vector_type(4)));
typedef float f32x4 __attribute__((ext_vector_type(4)));

constexpr int kB = 4;
constexpr int kS = 2048;
constexpr int kD = 1024;
constexpr int BM = 128, BN = 128, BK = 32;
constexpr int TILE_ELEMS = (BM + BN) * BK;   // 16KB per buffer

typedef __attribute__((address_space(1))) void as1void;
typedef __attribute__((address_space(3))) void as3void;

__device__ __forceinline__ void gload16(const void* g, void* l) {
  __builtin_amdgcn_global_load_lds((as1void*)g, (as3void*)l, 16, 0, 0);
}

__device__ __forceinline__ void wgbar() {
  asm volatile("" ::: "memory");
  __builtin_amdgcn_s_barrier();
  asm volatile("" ::: "memory");
}

// ===========================================================================
// R2-proven 2-phase mainloop (128x128, 4 waves, linear LDS). Untouched.
// ===========================================================================
__device__ __forceinline__ void gemm_mainloop(
    const bf16_t* __restrict__ A, int lda,
    const bf16_t* __restrict__ B, int ldb,
    int ksteps, bf16_t* lds, f32x4 acc[4][4]) {
  const int tid = threadIdx.x;
  const int w = tid >> 6, lane = tid & 63;
  const int srow = lane >> 2;
  const int scol = (lane & 3) << 3;
  const int wr = (w >> 1) << 6, wc = (w & 1) << 6;
  const int fr = lane & 15, kg = lane >> 4;

  const bf16_t* ga0 = A + (size_t)(w * 16 + srow) * lda + scol;
  const bf16_t* ga1 = A + (size_t)(64 + w * 16 + srow) * lda + scol;
  const bf16_t* gb0 = B + (size_t)(w * 16 + srow) * ldb + scol;
  const bf16_t* gb1 = B + (size_t)(64 + w * 16 + srow) * ldb + scol;
  const int oa0 = (w * 16) * BK;
  const int oa1 = (64 + w * 16) * BK;
  const int ob0 = BM * BK + (w * 16) * BK;
  const int ob1 = BM * BK + (64 + w * 16) * BK;

  gload16(ga0, lds + oa0);
  gload16(ga1, lds + oa1);
  gload16(gb0, lds + ob0);
  gload16(gb1, lds + ob1);
  ga0 += BK; ga1 += BK; gb0 += BK; gb1 += BK;
  __syncthreads();

  int cur = 0;
  for (int ks = 0; ks < ksteps; ++ks) {
    const int nxt = cur ^ 1;
    if (ks + 1 < ksteps) {
      bf16_t* nb = lds + nxt * TILE_ELEMS;
      gload16(ga0, nb + oa0);
      gload16(ga1, nb + oa1);
      gload16(gb0, nb + ob0);
      gload16(gb1, nb + ob1);
      ga0 += BK; ga1 += BK; gb0 += BK; gb1 += BK;
    }
    const bf16_t* cb = lds + cur * TILE_ELEMS;
    bf16x8 af[4], bfv[4];
#pragma unroll
    for (int m = 0; m < 4; ++m)
      af[m] = *(const bf16x8*)(cb + (wr + m * 16 + fr) * BK + kg * 8);
#pragma unroll
    for (int n = 0; n < 4; ++n)
      bfv[n] = *(const bf16x8*)(cb + BM * BK + (wc + n * 16 + fr) * BK + kg * 8);
#pragma unroll
    for (int m = 0; m < 4; ++m)
#pragma unroll
      for (int n = 0; n < 4; ++n)
        acc[m][n] = __builtin_amdgcn_mfma_f32_16x16x32_bf16(af[m], bfv[n],
                                                            acc[m][n], 0, 0, 0);
    __syncthreads();
    cur = nxt;
  }
}

// ===========================================================================
// R3-proven 256x256 / BK=64 / 8-wave / 512-thread 8-phase mainloop. Verbatim.
// ===========================================================================
__device__ __forceinline__ void gemm256_loop(
    const bf16_t* __restrict__ A, int lda,
    const bf16_t* __restrict__ B, int ldb,
    int nk, bf16_t* lds, f32x4 acc[8][4]) {
  const int tid = threadIdx.x;
  const int wid = tid >> 6, lane = tid & 63;
  const int wm = wid >> 2, wn = wid & 3;
  const int fr = lane & 15, kg = (lane >> 4) & 3;
  const int s_row = ((tid >> 7) << 4) | (tid & 15);
  const int s_col = ((tid >> 4) & 7) << 3;
  const bf16_t* pA = A + (size_t)s_row * lda + s_col;
  const bf16_t* pB = B + (size_t)s_row * ldb + s_col;
  const int ldst = wid << 9;

  auto stg = [&](int tt, int op, int h, int j) {
    const bf16_t* g = (op ? pB : pA) + (size_t)(h * 128 + j * 64) * (op ? ldb : lda)
                      + (size_t)tt * 64;
    bf16_t* d = lds + (((tt & 1) * 4 + op * 2 + h) * 8192) + j * 4096 + ldst;
    gload16(g, d);
  };

#pragma unroll
  for (int h = 0; h < 2; ++h)
#pragma unroll
    for (int j = 0; j < 2; ++j) { stg(0, 0, h, j); stg(0, 1, h, j); }
  stg(1, 1, 0, 0); stg(1, 1, 0, 1); stg(1, 1, 1, 0); stg(1, 1, 1, 1);
  stg(1, 0, 0, 0); stg(1, 0, 1, 0);
  asm volatile("s_waitcnt vmcnt(6)" ::: "memory");
  wgbar();

  const int arow = kg * 128 + fr * 8;
  for (int t = 0; t < nk; ++t) {
    const bf16_t* sb = lds + (t & 1) * 32768;
    const bf16_t* aslot = sb + wm * 8192;
    const bf16_t* bslot = sb + (2 + (wn >> 1)) * 8192 + (wn & 1) * 4096;
    bf16x8 bF[4][2];
#pragma unroll
    for (int q = 0; q < 4; ++q) {
      bf16x8 aF[2][2];
#pragma unroll
      for (int mi = 0; mi < 2; ++mi)
#pragma unroll
        for (int ks = 0; ks < 2; ++ks)
          aF[mi][ks] = *(const bf16x8*)(aslot + (2 * q + mi) * 1024 + ks * 512 + arow);
      if (q == 0) {
#pragma unroll
        for (int n = 0; n < 4; ++n)
#pragma unroll
          for (int ks = 0; ks < 2; ++ks)
            bF[n][ks] = *(const bf16x8*)(bslot + n * 1024 + ks * 512 + arow);
      }
      if (q == 0)      { if (t + 1 <= nk - 1) { stg(t + 1, 0, 0, 1); stg(t + 1, 0, 1, 1); } }
      else if (q == 1) { if (t + 2 <= nk - 1) { stg(t + 2, 1, 0, 0); stg(t + 2, 1, 0, 1); } }
      else if (q == 2) { if (t + 2 <= nk - 1) { stg(t + 2, 1, 1, 0); stg(t + 2, 1, 1, 1); } }
      else             { if (t + 2 <= nk - 1) { stg(t + 2, 0, 0, 0); stg(t + 2, 0, 1, 0); } }
      wgbar();
      __builtin_amdgcn_s_setprio(1);
#pragma unroll
      for (int mi = 0; mi < 2; ++mi)
#pragma unroll
        for (int n = 0; n < 4; ++n)
#pragma unroll
          for (int ks = 0; ks < 2; ++ks)
            acc[2 * q + mi][n] = __builtin_amdgcn_mfma_f32_16x16x32_bf16(
                aF[mi][ks], bF[n][ks], acc[2 * q + mi][n], 0, 0, 0);
      __builtin_amdgcn_s_setprio(0);
      asm volatile("s_waitcnt lgkmcnt(0)" ::: "memory");
      if (q == 3 && t < nk - 1) {
        if (t + 2 <= nk - 1) asm volatile("s_waitcnt vmcnt(6)" ::: "memory");
        else                 asm volatile("s_waitcnt vmcnt(0)" ::: "memory");
      }
      wgbar();
    }
  }
}

// C/D frag (16x16x32, verified m89/m91): col = lane&15, row = (lane>>4)*4 + i.

// ------------- QK projection: 256^2 8-phase, grid EXACTLY 256 (1 round) -----
__global__ __launch_bounds__(512, 2)
void k_qk256(const bf16_t* __restrict__ A, const bf16_t* __restrict__ WT,
             const float* __restrict__ bq, const float* __restrict__ bk,
             bf16_t* __restrict__ Qb, bf16_t* __restrict__ Kb) {
  __shared__ bf16_t lds[65536];
  const int id = blockIdx.x;                     // 256 = 32 mb x 8 nb
  const int swz = (id & 7) * 32 + (id >> 3);     // XCD-chunked (256%8==0)
  const int mb = swz >> 3, nb = swz & 7;
  const int m0 = mb * 256, n0 = nb * 256;
  f32x4 acc[8][4] = {};
  gemm256_loop(A + (size_t)m0 * kD, kD, WT + (size_t)n0 * kD, kD,
               kD / 64, lds, acc);
  const int lane = threadIdx.x & 63, wid = threadIdx.x >> 6;
  const int wm = wid >> 2, wn = wid & 3, fr = lane & 15, kgr = lane >> 4;
  const int which = n0 >> 10;                    // 256-tiles don't straddle 1024
  bf16_t* C = which == 0 ? Qb : Kb;
  const float* bias = which == 0 ? bq : bk;
#pragma unroll
  for (int n = 0; n < 4; ++n) {
    const int col = (n0 & 1023) + wn * 64 + n * 16 + fr;
    const float bvv = bias[col];
#pragma unroll
    for (int m = 0; m < 8; ++m)
#pragma unroll
      for (int i = 0; i < 4; ++i) {
        const int row = m0 + wm * 128 + m * 16 + kgr * 4 + i;
        C[(size_t)row * kD + col] = (bf16_t)(acc[m][n][i] + bvv);
      }
  }
}

// ------------- MERGED: scores (ids 0..543) + V projection (ids 544..1055) ---
// Scores tiles (equal length) dispatch first; V tiles backfill the 32 CUs
// that would otherwise carry a 3rd scores block -> better CU packing than
// two separate dispatches (544 on 1024 slots wastes the tail).
__global__ __launch_bounds__(256)
void k_scores_v(const bf16_t* __restrict__ Q, const bf16_t* __restrict__ K,
                float* __restrict__ Sc,
                const bf16_t* __restrict__ X, const bf16_t* __restrict__ WvT,
                const float* __restrict__ bv, bf16_t* __restrict__ VT) {
  __shared__ bf16_t lds[2 * TILE_ELEMS];
  const int id = blockIdx.x;
  const int tid = threadIdx.x, w = tid >> 6, lane = tid & 63;
  const int wr = (w >> 1) << 6, wc = (w & 1) << 6, fr = lane & 15, kg = lane >> 4;
  if (id < 544) {                                // ---- scores tile
    const int b = id / 136, t = id % 136;
    int by = (int)((sqrtf(8.f * t + 1.f) - 1.f) * 0.5f);
    while ((by + 1) * (by + 2) / 2 <= t) ++by;
    while (by * (by + 1) / 2 > t) --by;
    const int bx = t - by * (by + 1) / 2;
    const int m0 = by * BM, n0 = bx * BN;
    f32x4 acc[4][4] = {};
    gemm_mainloop(Q + (size_t)b * kS * kD + (size_t)m0 * kD, kD,
                  K + (size_t)b * kS * kD + (size_t)n0 * kD, kD, kD / BK, lds, acc);
    float* Sb = Sc + (size_t)b * kS * kS;
#pragma unroll
    for (int m = 0; m < 4; ++m)
#pragma unroll
      for (int n = 0; n < 4; ++n)
#pragma unroll
        for (int i = 0; i < 4; ++i) {
          const int row = m0 + wr + m * 16 + kg * 4 + i;
          const int col = n0 + wc + n * 16 + fr;
          Sb[(size_t)row * kS + col] = acc[m][n][i] * 0.03125f;
        }
  } else {                                       // ---- V projection tile
    const int vid = id - 544;                    // 512 = 64 mb x 8 nb
    const int swz = (vid & 7) * 64 + (vid >> 3);
    const int m0 = (swz >> 3) * BM, n0 = (swz & 7) * BN;
    f32x4 acc[4][4] = {};
    gemm_mainloop(X + (size_t)m0 * kD, kD, WvT + (size_t)n0 * kD, kD,
                  kD / BK, lds, acc);
#pragma unroll
    for (int n = 0; n < 4; ++n) {
      const int col = n0 + wc + n * 16 + fr;
      const float bvv = bv[col];
#pragma unroll
      for (int m = 0; m < 4; ++m)
#pragma unroll
        for (int i = 0; i < 4; ++i) {
          const int row = m0 + wr + m * 16 + kg * 4 + i;
          const int b = row >> 11, s = row & (kS - 1);
          VT[((size_t)b * kD + col) * kS + s] = (bf16_t)(acc[m][n][i] + bvv);
        }
    }
  }
}

// ------------- row softmax (causal): band-limited Pb zero-fill --------------
__global__ __launch_bounds__(256)
void k_softmax(float* __restrict__ P, bf16_t* __restrict__ Pb) {
  const int row = blockIdx.x;
  const int q = row & (kS - 1);
  float* p = P + (size_t)row * kS;
  bf16_t* pb = Pb + (size_t)row * kS;
  const int L = q + 1;
  __shared__ float buf[kS];
  __shared__ float red[8];
  const int tid = threadIdx.x;
  float4* b4 = (float4*)buf;
  const float4* p4 = (const float4*)p;
  if (tid * 4 < L) b4[tid] = p4[tid];
  if (1024 + tid * 4 < L) b4[tid + 256] = p4[tid + 256];
  __syncthreads();
  float mx = -1e30f;
  for (int k = tid; k < L; k += 256) mx = fmaxf(mx, buf[k]);
#pragma unroll
  for (int s2 = 32; s2 >= 1; s2 >>= 1) mx = fmaxf(mx, __shfl_xor(mx, s2));
  if ((tid & 63) == 0) red[tid >> 6] = mx;
  __syncthreads();
  mx = fmaxf(fmaxf(red[0], red[1]), fmaxf(red[2], red[3]));
  float sm = 0.f;
  for (int k = tid; k < L; k += 256) {
    const float e = __expf(buf[k] - mx);
    buf[k] = e;
    sm += e;
  }
#pragma unroll
  for (int s2 = 32; s2 >= 1; s2 >>= 1) sm += __shfl_xor(sm, s2);
  if ((tid & 63) == 0) red[4 + (tid >> 6)] = sm;
  __syncthreads();
  const float inv = 1.f / (red[4] + red[5] + red[6] + red[7]);
  for (int k = tid; k < L; k += 256) {
    const float v = buf[k] * inv;
    p[k] = v;
    pb[k] = (bf16_t)v;
  }
  // fp32 upper triangle: required output -> zero to kS.
  for (int k = L + tid; k < kS; k += 256) p[k] = 0.f;
  // bf16 P: PV reads only cols < (m0+128) for the panel at m0 = q&~127,
  // so zeros are needed only within the diagonal band.
  const int bandEnd = (q & ~127) + 128;
  for (int k = L + tid; k < bandEnd; k += 256) pb[k] = (bf16_t)0.f;
}

// ------------- attn_out = P*V: R2-exact (LPT, causal K-limit) ---------------
__global__ __launch_bounds__(256)
void k_gemm_pv(const bf16_t* __restrict__ P, const bf16_t* __restrict__ VT,
               bf16_t* __restrict__ AO) {
  const int bx = blockIdx.x, b = blockIdx.z;
  const int by = (int)gridDim.y - 1 - (int)blockIdx.y;
  __shared__ bf16_t lds[2 * TILE_ELEMS];
  const int m0 = by * BM, n0 = bx * BN;
  const int ksteps = (m0 + BM) / BK;
  f32x4 acc[4][4] = {};
  gemm_mainloop(P + (size_t)b * kS * kS + (size_t)m0 * kS, kS,
                VT + (size_t)b * kD * kS + (size_t)n0 * kS, kS, ksteps, lds, acc);
  bf16_t* AOb = AO + (size_t)b * kS * kD;
  const int tid = threadIdx.x, w = tid >> 6, lane = tid & 63;
  const int wr = (w >> 1) << 6, wc = (w & 1) << 6, fr = lane & 15, kg = lane >> 4;
#pragma unroll
  for (int m = 0; m < 4; ++m)
#pragma unroll
    for (int n = 0; n < 4; ++n)
#pragma unroll
      for (int i = 0; i < 4; ++i) {
        const int row = m0 + wr + m * 16 + kg * 4 + i;
        const int col = n0 + wc + n * 16 + fr;
        AOb[(size_t)row * kD + col] = (bf16_t)acc[m][n][i];
      }
}

// ------------- out = AO*Wo^T + bo: R2-exact ---------------------------------
__global__ __launch_bounds__(256)
void k_gemm_out(const bf16_t* __restrict__ A, const bf16_t* __restrict__ Bw,
                const float* __restrict__ bias, float* __restrict__ C) {
  __shared__ bf16_t lds[2 * TILE_ELEMS];
  const int id = blockIdx.x;                     // 512 = 64 mb x 8 nb
  const int swz = (id & 7) * 64 + (id >> 3);
  const int m0 = (swz >> 3) * BM, n0 = (swz & 7) * BN;
  f32x4 acc[4][4] = {};
  gemm_mainloop(A + (size_t)m0 * kD, kD, Bw + (size_t)n0 * kD, kD, kD / BK, lds, acc);
  const int tid = threadIdx.x, w = tid >> 6, lane = tid & 63;
  const int wr = (w >> 1) << 6, wc = (w & 1) << 6, fr = lane & 15, kg = lane >> 4;
#pragma unroll
  for (int n = 0; n < 4; ++n) {
    const int col = n0 + wc + n * 16 + fr;
    const float bv = bias[col];
#pragma unroll
    for (int m = 0; m < 4; ++m)
#pragma unroll
      for (int i = 0; i < 4; ++i) {
        const int row = m0 + wr + m * 16 + kg * 4 + i;
        C[(size_t)row * kD + col] = acc[m][n][i] + bv;
      }
  }
}

// ------------- fused prep: z<4 weight transpose->bf16, z==4 x->bf16 ---------
__global__ __launch_bounds__(256)
void k_prep(const float* __restrict__ X, bf16_t* __restrict__ Y,
            const float* __restrict__ W0, const float* __restrict__ W1,
            const float* __restrict__ W2, const float* __restrict__ W3,
            bf16_t* __restrict__ T0, bf16_t* __restrict__ T1,
            bf16_t* __restrict__ T2, bf16_t* __restrict__ T3) {
  const int tx = threadIdx.x & 31, ty = threadIdx.x >> 5;
  if (blockIdx.z == 4) {
    const size_t n4 = (size_t)kB * kS * kD / 4;
    size_t i = ((size_t)blockIdx.y * 32 + blockIdx.x) * 256 + threadIdx.x;
    const size_t stride = (size_t)1024 * 256;
    const float4* X4 = (const float4*)X;
    bf16x4* Y4 = (bf16x4*)Y;
    for (; i < n4; i += stride) {
      const float4 v = X4[i];
      bf16x4 o = {(bf16_t)v.x, (bf16_t)v.y, (bf16_t)v.z, (bf16_t)v.w};
      Y4[i] = o;
    }
    return;
  }
  const float* W = blockIdx.z == 0 ? W0 : blockIdx.z == 1 ? W1 : blockIdx.z == 2 ? W2 : W3;
  bf16_t* T = blockIdx.z == 0 ? T0 : blockIdx.z == 1 ? T1 : blockIdx.z == 2 ? T2 : T3;
  __shared__ float t[32][33];
  const int x0 = blockIdx.x * 32, y0 = blockIdx.y * 32;
#pragma unroll
  for (int j = 0; j < 4; ++j)
    t[ty + 8 * j][tx] = W[(size_t)(y0 + ty + 8 * j) * kD + x0 + tx];
  __syncthreads();
#pragma unroll
  for (int j = 0; j < 4; ++j)
    T[(size_t)(x0 + ty + 8 * j) * kD + y0 + tx] = (bf16_t)t[tx][ty + 8 * j];
}

extern "C" void kernel_launch(void* const* d_in, const int* in_sizes, int n_in,
                              void* d_out, int out_size, void* d_ws, size_t ws_size,
                              hipStream_t stream) {
  (void)in_sizes; (void)n_in; (void)out_size; (void)ws_size;
  const float* x  = (const float*)d_in[0];
  // d_in[1] = mask: tril(ones) by construction -> causality hardcoded
  const float* Wq = (const float*)d_in[2];
  const float* bq = (const float*)d_in[3];
  const float* Wk = (const float*)d_in[4];
  const float* bk = (const float*)d_in[5];
  const float* Wv = (const float*)d_in[6];
  const float* bv = (const float*)d_in[7];
  const float* Wo = (const float*)d_in[8];
  const float* bo = (const float*)d_in[9];

  float* out  = (float*)d_out;                       // [4,2048,1024] fp32
  float* Pout = out + (size_t)kB * kS * kD;          // [4,2048,2048] fp32

  bf16_t* WqT = (bf16_t*)d_ws;                       // [WqT;WkT] packed for k_qk256
  bf16_t* WkT = WqT + (size_t)kD * kD;
  bf16_t* WvT = WkT + (size_t)kD * kD;
  bf16_t* WoT = WvT + (size_t)kD * kD;
  bf16_t* Qb  = WoT + (size_t)kD * kD;
  bf16_t* Kb  = Qb + (size_t)kB * kS * kD;
  bf16_t* VTb = Kb + (size_t)kB * kS * kD;
  bf16_t* Pb  = VTb + (size_t)kB * kS * kD;
  bf16_t* AOb = Pb + (size_t)kB * kS * kS;
  bf16_t* xb  = AOb + (size_t)kB * kS * kD;

  k_prep<<<dim3(32, 32, 5), 256, 0, stream>>>(x, xb, Wq, Wk, Wv, Wo,
                                              WqT, WkT, WvT, WoT);
  k_qk256<<<256, 512, 0, stream>>>(xb, WqT, bq, bk, Qb, Kb);
  k_scores_v<<<1056, 256, 0, stream>>>(Qb, Kb, Pout, xb, WvT, bv, VTb);
  k_softmax<<<kB * kS, 256, 0, stream>>>(Pout, Pb);
  k_gemm_pv<<<dim3(8, 16, kB), 256, 0, stream>>>(Pb, VTb, AOb);
  k_gemm_out<<<512, 256, 0, stream>>>(AOb, WoT, bo, out);
}